// Round 7
// baseline (173.203 us; speedup 1.0000x reference)
//
#include <hip/hip_runtime.h>
#include <hip/hip_bf16.h>

// Problem constants: B=2, S=128, D=512, H=8, Dh=64. All I/O float32 (R2/R3 evidence).
#define B_  2
#define S_  128
#define D_  512
#define H_  8
#define DH_ 64
#define IGNORE_VAL (-1.0e6f)
#define QB  4        // queries per tri block (interleaved: q = qg + 32*qq)

#define XT_ST 72     // ushort stride for row-major A tiles (16B-aligned rows)
#define WT_ST 66     // ushort stride for k-major W tiles (2-way banks on strided u16 reads)

typedef __attribute__((ext_vector_type(8))) short bf16x8;   // MFMA A/B frag (4 VGPRs)
typedef __attribute__((ext_vector_type(4))) float f32x4;    // MFMA C/D frag

__device__ __forceinline__ unsigned short f2bf(float f) {
    unsigned int x = __float_as_uint(f);
    return (unsigned short)((x + 0x7fffu + ((x >> 16) & 1u)) >> 16);
}

// ---------------- Kernel 1: fused projection GEMM (bf16 MFMA) ---------------
// A = x (256 x 512), virtual W = [W_kkq | Wv_a | Wv_b] (512 x 2560).
// Tile 32 rows x 64 cols, BK=64, grid (40, 8) = 320 blocks, 4 waves.
// cb: 0..7 k1 | 8..15 k2 | 16..23 q | 24..31 va | 32..39 vb (head n = cb&7).
// k1/q/va/vb head-major f32; k2 head-major bf16.
__global__ __launch_bounds__(256) void proj_kernel(
    const float* __restrict__ x,
    const float* __restrict__ W_kkq, const float* __restrict__ b_kkq,
    const float* __restrict__ Wv_a,  const float* __restrict__ Wv_b,
    float* __restrict__ k1_ws, unsigned short* __restrict__ k2bf, float* __restrict__ q_ws,
    float* __restrict__ va_ws, float* __restrict__ vb_ws)
{
    __shared__ __align__(16) unsigned short xs[32 * XT_ST];   // 4608 B
    __shared__ __align__(16) unsigned short Wt[64 * WT_ST];   // 8448 B

    const int cb = blockIdx.x;           // 0..39
    const int rb = blockIdx.y;           // 0..7 (32 rows)
    const int tid = threadIdx.x;
    const int lane = tid & 63, wvx = tid >> 6;
    const int n16 = lane & 15, quad = lane >> 4;

    const int part = cb >> 3;            // 0 k1, 1 k2, 2 q, 3 va, 4 vb
    const float* Wbase; int wstride; int wcoloff;
    if (part <= 2) { Wbase = W_kkq; wstride = 1536; wcoloff = cb * 64; }
    else if (part == 3) { Wbase = Wv_a; wstride = 512; wcoloff = (cb - 24) * 64; }
    else { Wbase = Wv_b; wstride = 512; wcoloff = (cb - 32) * 64; }

    f32x4 acc[2];
    acc[0] = (f32x4){0.f, 0.f, 0.f, 0.f};
    acc[1] = (f32x4){0.f, 0.f, 0.f, 0.f};

    for (int k0 = 0; k0 < D_; k0 += 64) {
        {   // stage x tile: 32 rows x 64 k, f32 -> bf16, one uint4/thread
            const int m = tid >> 3, k8 = (tid & 7) * 8;
            const float* src = x + (size_t)(rb * 32 + m) * D_ + k0 + k8;
            const float4 a = *reinterpret_cast<const float4*>(src);
            const float4 b4 = *reinterpret_cast<const float4*>(src + 4);
            uint4 pk;
            pk.x = f2bf(a.x)  | ((unsigned)f2bf(a.y)  << 16);
            pk.y = f2bf(a.z)  | ((unsigned)f2bf(a.w)  << 16);
            pk.z = f2bf(b4.x) | ((unsigned)f2bf(b4.y) << 16);
            pk.w = f2bf(b4.z) | ((unsigned)f2bf(b4.w) << 16);
            *reinterpret_cast<uint4*>(&xs[m * XT_ST + k8]) = pk;
        }
        {   // stage W tile k-major: Wt[k][n], 64 k x 64 n, coalesced reads
#pragma unroll
            for (int p = 0; p < 4; ++p) {
                const int k = p * 16 + (tid >> 4);
                const int nb = (tid & 15) * 4;
                const float4 v = *reinterpret_cast<const float4*>(
                    Wbase + (size_t)(k0 + k) * wstride + wcoloff + nb);
                *reinterpret_cast<unsigned int*>(&Wt[k * WT_ST + nb]) =
                    f2bf(v.x) | ((unsigned)f2bf(v.y) << 16);
                *reinterpret_cast<unsigned int*>(&Wt[k * WT_ST + nb + 2]) =
                    f2bf(v.z) | ((unsigned)f2bf(v.w) << 16);
            }
        }
        __syncthreads();
#pragma unroll
        for (int kk = 0; kk < 2; ++kk) {
            bf16x8 bf;
#pragma unroll
            for (int j = 0; j < 8; ++j)
                bf[j] = (short)Wt[(kk * 32 + quad * 8 + j) * WT_ST + wvx * 16 + n16];
#pragma unroll
            for (int mt = 0; mt < 2; ++mt) {
                const bf16x8 af = *reinterpret_cast<const bf16x8*>(
                    &xs[(mt * 16 + n16) * XT_ST + kk * 32 + quad * 8]);
                acc[mt] = __builtin_amdgcn_mfma_f32_16x16x32_bf16(af, bf, acc[mt], 0, 0, 0);
            }
        }
        __syncthreads();
    }

    const int n_head = cb & 7;
    const int h = wvx * 16 + n16;
    const float bias = (part <= 2) ? b_kkq[cb * 64 + h] : 0.f;
    float* Obase = (part == 0) ? k1_ws : (part == 2) ? q_ws
                 : (part == 3) ? va_ws : vb_ws;
#pragma unroll
    for (int mt = 0; mt < 2; ++mt)
#pragma unroll
        for (int r = 0; r < 4; ++r) {
            const int row = rb * 32 + mt * 16 + quad * 4 + r;   // b*128 + s
            const int b = row >> 7, s = row & 127;
            const size_t o = (((size_t)(b * H_ + n_head) * S_ + s) << 6) + h;
            const float val = acc[mt][r] + bias;
            if (part == 1) k2bf[o] = f2bf(val);
            else           Obase[o] = val;
        }
}

// ---------------- Kernel 2: MFMA tri-scores + softmax marginals + z ---------
// Block = (4 interleaved q's, n, b), 256 thr = 4 waves. grid (32, 8, 2) = 512.
// q = qg + 32*qq  ->  causal skip: only nt <= (q>>4) column-tiles contribute;
// interleave balances Sum(ntmax) to 16 (qg<16) / 20 (qg>=16) of 32 tiles (~45% cut).
// No max-shift: |scores/64| small; masked -> exp underflows to exactly 0.
#define K2S 72   // ushort stride for k2 LDS rows
__global__ __launch_bounds__(256) void tri_kernel(
    const float* __restrict__ k1_ws, const unsigned short* __restrict__ k2bf,
    const float* __restrict__ q_ws,
    const float* __restrict__ va_ws, const float* __restrict__ vb_ws,
    const float* __restrict__ b_v,
    unsigned short* __restrict__ z_bf)
{
    const int qg = blockIdx.x;           // 0..31
    const int n = blockIdx.y;
    const int b = blockIdx.z;
    const int head = b * H_ + n;
    const float* k1h = k1_ws + (size_t)head * S_ * DH_;
    const unsigned short* k2hb = k2bf + (size_t)head * S_ * DH_;
    const float* qh = q_ws + (size_t)head * S_ * DH_;
    const float* va_h = va_ws + (size_t)head * S_ * DH_;
    const float* vb_h = vb_ws + (size_t)head * S_ * DH_;

    __shared__ __align__(16) unsigned short k2s[S_ * K2S];   // 18432 B
    __shared__ __align__(16) float qv[QB][DH_];
    __shared__ float Asm[QB][S_];
    __shared__ float Atm[QB][S_];
    __shared__ float Atp[QB][4][S_];
    __shared__ float reds[QB][4];
    __shared__ float zred[4][QB][DH_];

    const int tid = threadIdx.x;
    const int lane = tid & 63, wv = tid >> 6;
    const int row16 = lane & 15, quad = lane >> 4;

    if (tid < QB * DH_)
        qv[tid >> 6][tid & 63] = qh[(size_t)(qg + 32 * (tid >> 6)) * DH_ + (tid & 63)];
#pragma unroll
    for (int it = 0; it < 4; ++it) {
        const int i8 = (tid + it * 256) * 8;
        const int r = i8 >> 6, c = i8 & 63;
        uint4 v = *reinterpret_cast<const uint4*>(k2hb + i8);
        *reinterpret_cast<uint4*>(&k2s[r * K2S + c]) = v;
    }

    // k1 f32 fragments, kept across the q-loop. A[m=lane&15][k=quad*8+j]
    float k1f[2][2][8];
#pragma unroll
    for (int mt = 0; mt < 2; ++mt) {
        const int srow = (wv * 2 + mt) * 16 + row16;
#pragma unroll
        for (int kk = 0; kk < 2; ++kk) {
            const int k = kk * 32 + quad * 8;
            const float4 u0 = *reinterpret_cast<const float4*>(k1h + (size_t)srow * DH_ + k);
            const float4 u1 = *reinterpret_cast<const float4*>(k1h + (size_t)srow * DH_ + k + 4);
            k1f[mt][kk][0] = u0.x; k1f[mt][kk][1] = u0.y; k1f[mt][kk][2] = u0.z; k1f[mt][kk][3] = u0.w;
            k1f[mt][kk][4] = u1.x; k1f[mt][kk][5] = u1.y; k1f[mt][kk][6] = u1.z; k1f[mt][kk][7] = u1.w;
        }
    }
    __syncthreads();

    for (int qq = 0; qq < QB; ++qq) {
        const int qidx = qg + 32 * qq;
        const int ntmax = (qidx >> 4) + 1;     // causal: tiles nt >= ntmax fully masked

        bf16x8 afrag[2][2];
#pragma unroll
        for (int mt = 0; mt < 2; ++mt)
#pragma unroll
            for (int kk = 0; kk < 2; ++kk) {
                const int k = kk * 32 + quad * 8;
                bf16x8 f;
#pragma unroll
                for (int j = 0; j < 8; ++j)
                    f[j] = (short)f2bf(k1f[mt][kk][j] * qv[qq][k + j]);
                afrag[mt][kk] = f;
            }

        f32x4 acc[2][8];
#pragma unroll
        for (int mt = 0; mt < 2; ++mt)
#pragma unroll
            for (int nt = 0; nt < 8; ++nt) acc[mt][nt] = (f32x4){0.f, 0.f, 0.f, 0.f};
        for (int nt = 0; nt < ntmax; ++nt) {
#pragma unroll
            for (int kk = 0; kk < 2; ++kk) {
                bf16x8 bfrag = *reinterpret_cast<const bf16x8*>(
                    &k2s[(nt * 16 + row16) * K2S + kk * 32 + quad * 8]);
                acc[0][nt] = __builtin_amdgcn_mfma_f32_16x16x32_bf16(afrag[0][kk], bfrag, acc[0][nt], 0, 0, 0);
                acc[1][nt] = __builtin_amdgcn_mfma_f32_16x16x32_bf16(afrag[1][kk], bfrag, acc[1][nt], 0, 0, 0);
            }
        }

        float rs[2][4], cs[8];
#pragma unroll
        for (int nt = 0; nt < 8; ++nt) cs[nt] = 0.f;
#pragma unroll
        for (int mt = 0; mt < 2; ++mt)
#pragma unroll
            for (int r = 0; r < 4; ++r) rs[mt][r] = 0.f;
        for (int nt = 0; nt < ntmax; ++nt) {
            const int t = nt * 16 + row16;
            const bool msk = (t > qidx);
#pragma unroll
            for (int mt = 0; mt < 2; ++mt)
#pragma unroll
                for (int r = 0; r < 4; ++r) {
                    float v = msk ? IGNORE_VAL : acc[mt][nt][r];
                    float p = __expf(v * (1.f / 64.f));
                    rs[mt][r] += p;
                    cs[nt] += p;
                }
        }

        // row sums across lane bits 0..3
#pragma unroll
        for (int m = 1; m < 16; m <<= 1)
#pragma unroll
            for (int mt = 0; mt < 2; ++mt)
#pragma unroll
                for (int r = 0; r < 4; ++r) rs[mt][r] += __shfl_xor(rs[mt][r], m, 64);
        if (row16 == 0) {
#pragma unroll
            for (int mt = 0; mt < 2; ++mt)
#pragma unroll
                for (int r = 0; r < 4; ++r)
                    Asm[qq][(wv * 2 + mt) * 16 + quad * 4 + r] = rs[mt][r];
        }

        // col sums across lane bits 4..5 -> per-wave partials (inactive nt stay 0)
        for (int nt = 0; nt < ntmax; ++nt)
#pragma unroll
            for (int m = 16; m < 64; m <<= 1) cs[nt] += __shfl_xor(cs[nt], m, 64);
        if (quad == 0) {
#pragma unroll
            for (int nt = 0; nt < 8; ++nt) Atp[qq][wv][nt * 16 + row16] = cs[nt];
        }

        float tot = rs[0][0] + rs[0][1] + rs[0][2] + rs[0][3]
                  + rs[1][0] + rs[1][1] + rs[1][2] + rs[1][3];
#pragma unroll
        for (int m = 16; m < 64; m <<= 1) tot += __shfl_xor(tot, m, 64);
        if (lane == 0) reds[qq][wv] = tot;
    }
    __syncthreads();

    for (int i = tid; i < QB * S_; i += 256) {
        const int qq = i >> 7, t = i & 127;
        Atm[qq][t] = Atp[qq][0][t] + Atp[qq][1][t] + Atp[qq][2][t] + Atp[qq][3][t];
    }
    __syncthreads();

    // epilogue, s-major: read va/vb rows once, FMA into 4 q-accumulators
    {
        const int h = tid & 63, w = tid >> 6;
        float za[QB] = {0.f, 0.f, 0.f, 0.f};
        for (int i = 0; i < 32; ++i) {
            const int s = w * 32 + i;
            const float va_v = va_h[(size_t)s * DH_ + h];
            const float vb_v = vb_h[(size_t)s * DH_ + h];
#pragma unroll
            for (int qq = 0; qq < QB; ++qq)
                za[qq] += Asm[qq][s] * va_v + Atm[qq][s] * vb_v;
        }
#pragma unroll
        for (int qq = 0; qq < QB; ++qq) zred[w][qq][h] = za[qq];
    }
    __syncthreads();

    {
        const int qq = tid >> 6, h = tid & 63;
        const float Zv = reds[qq][0] + reds[qq][1] + reds[qq][2] + reds[qq][3];
        float zv = zred[0][qq][h] + zred[1][qq][h] + zred[2][qq][h] + zred[3][qq][h];
        zv = zv / Zv + b_v[n * DH_ + h];
        z_bf[((size_t)(b * S_ + qg + 32 * qq) * (H_ * DH_)) + n * DH_ + h] = f2bf(zv);
    }
}

// ---------------- Kernel 3: out = z @ W_out + b_out (bf16 MFMA) -------------
// A = z_bf (256 x 512 bf16), W_out (512 x 512 f32). Tile 16 x 64, BK=64,
// grid (8, 16) = 128 blocks, 4 waves (wave w: cols w*16..w*16+15).
__global__ __launch_bounds__(256) void out_kernel(
    const unsigned short* __restrict__ z_bf,
    const float* __restrict__ W_out, const float* __restrict__ b_out,
    float* __restrict__ out)
{
    __shared__ __align__(16) unsigned short zs[16 * XT_ST];   // 2304 B
    __shared__ __align__(16) unsigned short Wt[64 * WT_ST];   // 8448 B

    const int cb = blockIdx.x;           // 0..7 (64 cols)
    const int rb = blockIdx.y;           // 0..15 (16 rows)
    const int tid = threadIdx.x;
    const int lane = tid & 63, wvx = tid >> 6;
    const int n16 = lane & 15, quad = lane >> 4;

    f32x4 acc = (f32x4){0.f, 0.f, 0.f, 0.f};

    for (int k0 = 0; k0 < 512; k0 += 64) {
        {   // stage z tile: 16 rows x 64 k, raw bf16 copy (uint2 = 4 elems/thread)
            const int m = tid >> 4, k4 = (tid & 15) * 4;
            uint2 v = *reinterpret_cast<const uint2*>(
                z_bf + (size_t)(rb * 16 + m) * 512 + k0 + k4);
            *reinterpret_cast<uint2*>(&zs[m * XT_ST + k4]) = v;
        }
        {   // stage W_out tile k-major
#pragma unroll
            for (int p = 0; p < 4; ++p) {
                const int k = p * 16 + (tid >> 4);
                const int nb = (tid & 15) * 4;
                const float4 v = *reinterpret_cast<const float4*>(
                    W_out + (size_t)(k0 + k) * 512 + cb * 64 + nb);
                *reinterpret_cast<unsigned int*>(&Wt[k * WT_ST + nb]) =
                    f2bf(v.x) | ((unsigned)f2bf(v.y) << 16);
                *reinterpret_cast<unsigned int*>(&Wt[k * WT_ST + nb + 2]) =
                    f2bf(v.z) | ((unsigned)f2bf(v.w) << 16);
            }
        }
        __syncthreads();
#pragma unroll
        for (int kk = 0; kk < 2; ++kk) {
            bf16x8 bf;
#pragma unroll
            for (int j = 0; j < 8; ++j)
                bf[j] = (short)Wt[(kk * 32 + quad * 8 + j) * WT_ST + wvx * 16 + n16];
            const bf16x8 af = *reinterpret_cast<const bf16x8*>(
                &zs[n16 * XT_ST + kk * 32 + quad * 8]);
            acc = __builtin_amdgcn_mfma_f32_16x16x32_bf16(af, bf, acc, 0, 0, 0);
        }
        __syncthreads();
    }

    const int c = cb * 64 + wvx * 16 + n16;
    const float bias = b_out[c];
#pragma unroll
    for (int r = 0; r < 4; ++r) {
        const int row = rb * 16 + quad * 4 + r;
        out[(size_t)row * 512 + c] = acc[r] + bias;
    }
}

// ---------------------------------------------------------------------------
extern "C" void kernel_launch(void* const* d_in, const int* in_sizes, int n_in,
                              void* d_out, int out_size, void* d_ws, size_t ws_size,
                              hipStream_t stream) {
    const float* x     = (const float*)d_in[0];
    const float* W_kkq = (const float*)d_in[1];
    const float* b_kkq = (const float*)d_in[2];
    const float* Wv_a  = (const float*)d_in[3];
    const float* Wv_b  = (const float*)d_in[4];
    const float* b_v   = (const float*)d_in[5];
    const float* W_out = (const float*)d_in[6];
    const float* b_out = (const float*)d_in[7];
    float* out = (float*)d_out;

    const size_t HE = (size_t)B_ * H_ * S_ * DH_;   // 131072
    float* ws = (float*)d_ws;
    float* k1_ws = ws;
    float* q_ws  = ws + HE;
    float* va_ws = ws + 2 * HE;
    float* vb_ws = ws + 3 * HE;
    unsigned short* k2bf = (unsigned short*)(ws + 4 * HE);          // HE ushorts
    unsigned short* z_bf = (unsigned short*)(ws + 4 * HE) + HE;     // HE ushorts

    proj_kernel<<<dim3(40, 8), 256, 0, stream>>>(x, W_kkq, b_kkq, Wv_a, Wv_b,
                                                 k1_ws, k2bf, q_ws, va_ws, vb_ws);
    tri_kernel<<<dim3(32, H_, B_), 256, 0, stream>>>(k1_ws, k2bf, q_ws,
                                                     va_ws, vb_ws, b_v, z_bf);
    out_kernel<<<dim3(8, 16), 256, 0, stream>>>(z_bf, W_out, b_out, out);
}

// Round 8
// 112.661 us; speedup vs baseline: 1.5374x; 1.5374x over previous
//
#include <hip/hip_runtime.h>
#include <hip/hip_bf16.h>

// Problem constants: B=2, S=128, D=512, H=8, Dh=64. All I/O float32 (R2/R3 evidence).
#define B_  2
#define S_  128
#define D_  512
#define H_  8
#define DH_ 64
#define IGNORE_VAL (-1.0e6f)
#define QB  4        // queries per tri block (interleaved: q = qg + 32*qq)

#define XT_ST 72     // ushort stride for row-major A tiles (16B-aligned rows)
#define WT_ST 66     // ushort stride for k-major W tiles (2-way banks on strided u16 reads)

typedef __attribute__((ext_vector_type(8))) short bf16x8;   // MFMA A/B frag (4 VGPRs)
typedef __attribute__((ext_vector_type(4))) float f32x4;    // MFMA C/D frag

__device__ __forceinline__ unsigned short f2bf(float f) {
    unsigned int x = __float_as_uint(f);
    return (unsigned short)((x + 0x7fffu + ((x >> 16) & 1u)) >> 16);
}

// ---------------- Kernel 1: fused projection GEMM (bf16 MFMA) ---------------
// A = x (256 x 512), virtual W = [W_kkq | Wv_a | Wv_b] (512 x 2560).
// Tile 32 rows x 64 cols, BK=64, grid (40, 8) = 320 blocks, 4 waves.
// cb: 0..7 k1 | 8..15 k2 | 16..23 q | 24..31 va | 32..39 vb (head n = cb&7).
// k1/q/va/vb head-major f32; k2 head-major bf16.
__global__ __launch_bounds__(256) void proj_kernel(
    const float* __restrict__ x,
    const float* __restrict__ W_kkq, const float* __restrict__ b_kkq,
    const float* __restrict__ Wv_a,  const float* __restrict__ Wv_b,
    float* __restrict__ k1_ws, unsigned short* __restrict__ k2bf, float* __restrict__ q_ws,
    float* __restrict__ va_ws, float* __restrict__ vb_ws)
{
    __shared__ __align__(16) unsigned short xs[32 * XT_ST];   // 4608 B
    __shared__ __align__(16) unsigned short Wt[64 * WT_ST];   // 8448 B

    const int cb = blockIdx.x;           // 0..39
    const int rb = blockIdx.y;           // 0..7 (32 rows)
    const int tid = threadIdx.x;
    const int lane = tid & 63, wvx = tid >> 6;
    const int n16 = lane & 15, quad = lane >> 4;

    const int part = cb >> 3;            // 0 k1, 1 k2, 2 q, 3 va, 4 vb
    const float* Wbase; int wstride; int wcoloff;
    if (part <= 2) { Wbase = W_kkq; wstride = 1536; wcoloff = cb * 64; }
    else if (part == 3) { Wbase = Wv_a; wstride = 512; wcoloff = (cb - 24) * 64; }
    else { Wbase = Wv_b; wstride = 512; wcoloff = (cb - 32) * 64; }

    f32x4 acc[2];
    acc[0] = (f32x4){0.f, 0.f, 0.f, 0.f};
    acc[1] = (f32x4){0.f, 0.f, 0.f, 0.f};

    for (int k0 = 0; k0 < D_; k0 += 64) {
        {   // stage x tile: 32 rows x 64 k, f32 -> bf16, one uint4/thread
            const int m = tid >> 3, k8 = (tid & 7) * 8;
            const float* src = x + (size_t)(rb * 32 + m) * D_ + k0 + k8;
            const float4 a = *reinterpret_cast<const float4*>(src);
            const float4 b4 = *reinterpret_cast<const float4*>(src + 4);
            uint4 pk;
            pk.x = f2bf(a.x)  | ((unsigned)f2bf(a.y)  << 16);
            pk.y = f2bf(a.z)  | ((unsigned)f2bf(a.w)  << 16);
            pk.z = f2bf(b4.x) | ((unsigned)f2bf(b4.y) << 16);
            pk.w = f2bf(b4.z) | ((unsigned)f2bf(b4.w) << 16);
            *reinterpret_cast<uint4*>(&xs[m * XT_ST + k8]) = pk;
        }
        {   // stage W tile k-major: Wt[k][n], 64 k x 64 n, coalesced reads
#pragma unroll
            for (int p = 0; p < 4; ++p) {
                const int k = p * 16 + (tid >> 4);
                const int nb = (tid & 15) * 4;
                const float4 v = *reinterpret_cast<const float4*>(
                    Wbase + (size_t)(k0 + k) * wstride + wcoloff + nb);
                *reinterpret_cast<unsigned int*>(&Wt[k * WT_ST + nb]) =
                    f2bf(v.x) | ((unsigned)f2bf(v.y) << 16);
                *reinterpret_cast<unsigned int*>(&Wt[k * WT_ST + nb + 2]) =
                    f2bf(v.z) | ((unsigned)f2bf(v.w) << 16);
            }
        }
        __syncthreads();
#pragma unroll
        for (int kk = 0; kk < 2; ++kk) {
            bf16x8 bf;
#pragma unroll
            for (int j = 0; j < 8; ++j)
                bf[j] = (short)Wt[(kk * 32 + quad * 8 + j) * WT_ST + wvx * 16 + n16];
#pragma unroll
            for (int mt = 0; mt < 2; ++mt) {
                const bf16x8 af = *reinterpret_cast<const bf16x8*>(
                    &xs[(mt * 16 + n16) * XT_ST + kk * 32 + quad * 8]);
                acc[mt] = __builtin_amdgcn_mfma_f32_16x16x32_bf16(af, bf, acc[mt], 0, 0, 0);
            }
        }
        __syncthreads();
    }

    const int n_head = cb & 7;
    const int h = wvx * 16 + n16;
    const float bias = (part <= 2) ? b_kkq[cb * 64 + h] : 0.f;
    float* Obase = (part == 0) ? k1_ws : (part == 2) ? q_ws
                 : (part == 3) ? va_ws : vb_ws;
#pragma unroll
    for (int mt = 0; mt < 2; ++mt)
#pragma unroll
        for (int r = 0; r < 4; ++r) {
            const int row = rb * 32 + mt * 16 + quad * 4 + r;   // b*128 + s
            const int b = row >> 7, s = row & 127;
            const size_t o = (((size_t)(b * H_ + n_head) * S_ + s) << 6) + h;
            const float val = acc[mt][r] + bias;
            if (part == 1) k2bf[o] = f2bf(val);
            else           Obase[o] = val;
        }
}

// ---------------- Kernel 2: MFMA tri-scores + softmax marginals + z ---------
// Block = (4 interleaved q's, n, b), 256 thr = 4 waves. grid (32, 8, 2) = 512.
// q = qg + 32*qq. Causal skip via FULLY-UNROLLED nt loops with wave-uniform
// guard (nt <= ntlim): runtime loop bounds in R7 demoted acc[] to scratch
// (VGPR 56, 155 MB spill writes). Compile-time indices keep arrays in VGPRs;
// guard is a scalar branch (ntlim block-uniform).
#define K2S 72   // ushort stride for k2 LDS rows
__global__ __launch_bounds__(256) void tri_kernel(
    const float* __restrict__ k1_ws, const unsigned short* __restrict__ k2bf,
    const float* __restrict__ q_ws,
    const float* __restrict__ va_ws, const float* __restrict__ vb_ws,
    const float* __restrict__ b_v,
    unsigned short* __restrict__ z_bf)
{
    const int qg = blockIdx.x;           // 0..31
    const int n = blockIdx.y;
    const int b = blockIdx.z;
    const int head = b * H_ + n;
    const float* k1h = k1_ws + (size_t)head * S_ * DH_;
    const unsigned short* k2hb = k2bf + (size_t)head * S_ * DH_;
    const float* qh = q_ws + (size_t)head * S_ * DH_;
    const float* va_h = va_ws + (size_t)head * S_ * DH_;
    const float* vb_h = vb_ws + (size_t)head * S_ * DH_;

    __shared__ __align__(16) unsigned short k2s[S_ * K2S];   // 18432 B
    __shared__ __align__(16) float qv[QB][DH_];
    __shared__ float Asm[QB][S_];
    __shared__ float Atm[QB][S_];
    __shared__ float Atp[QB][4][S_];
    __shared__ float reds[QB][4];
    __shared__ float zred[4][QB][DH_];

    const int tid = threadIdx.x;
    const int lane = tid & 63, wv = tid >> 6;
    const int row16 = lane & 15, quad = lane >> 4;

    if (tid < QB * DH_)
        qv[tid >> 6][tid & 63] = qh[(size_t)(qg + 32 * (tid >> 6)) * DH_ + (tid & 63)];
#pragma unroll
    for (int it = 0; it < 4; ++it) {
        const int i8 = (tid + it * 256) * 8;
        const int r = i8 >> 6, c = i8 & 63;
        uint4 v = *reinterpret_cast<const uint4*>(k2hb + i8);
        *reinterpret_cast<uint4*>(&k2s[r * K2S + c]) = v;
    }

    // k1 f32 fragments, kept across the q-loop. A[m=lane&15][k=quad*8+j]
    float k1f[2][2][8];
#pragma unroll
    for (int mt = 0; mt < 2; ++mt) {
        const int srow = (wv * 2 + mt) * 16 + row16;
#pragma unroll
        for (int kk = 0; kk < 2; ++kk) {
            const int k = kk * 32 + quad * 8;
            const float4 u0 = *reinterpret_cast<const float4*>(k1h + (size_t)srow * DH_ + k);
            const float4 u1 = *reinterpret_cast<const float4*>(k1h + (size_t)srow * DH_ + k + 4);
            k1f[mt][kk][0] = u0.x; k1f[mt][kk][1] = u0.y; k1f[mt][kk][2] = u0.z; k1f[mt][kk][3] = u0.w;
            k1f[mt][kk][4] = u1.x; k1f[mt][kk][5] = u1.y; k1f[mt][kk][6] = u1.z; k1f[mt][kk][7] = u1.w;
        }
    }
    __syncthreads();

    for (int qq = 0; qq < QB; ++qq) {
        const int qidx = qg + 32 * qq;
        const int ntlim = qidx >> 4;        // tiles nt > ntlim are fully masked (exp = 0)

        bf16x8 afrag[2][2];
#pragma unroll
        for (int mt = 0; mt < 2; ++mt)
#pragma unroll
            for (int kk = 0; kk < 2; ++kk) {
                const int k = kk * 32 + quad * 8;
                bf16x8 f;
#pragma unroll
                for (int j = 0; j < 8; ++j)
                    f[j] = (short)f2bf(k1f[mt][kk][j] * qv[qq][k + j]);
                afrag[mt][kk] = f;
            }

        f32x4 acc[2][8];
#pragma unroll
        for (int mt = 0; mt < 2; ++mt)
#pragma unroll
            for (int nt = 0; nt < 8; ++nt) acc[mt][nt] = (f32x4){0.f, 0.f, 0.f, 0.f};
#pragma unroll
        for (int nt = 0; nt < 8; ++nt) {
            if (nt <= ntlim) {              // wave-uniform guard, indices compile-time
#pragma unroll
                for (int kk = 0; kk < 2; ++kk) {
                    bf16x8 bfrag = *reinterpret_cast<const bf16x8*>(
                        &k2s[(nt * 16 + row16) * K2S + kk * 32 + quad * 8]);
                    acc[0][nt] = __builtin_amdgcn_mfma_f32_16x16x32_bf16(afrag[0][kk], bfrag, acc[0][nt], 0, 0, 0);
                    acc[1][nt] = __builtin_amdgcn_mfma_f32_16x16x32_bf16(afrag[1][kk], bfrag, acc[1][nt], 0, 0, 0);
                }
            }
        }

        float rs[2][4], cs[8];
#pragma unroll
        for (int nt = 0; nt < 8; ++nt) cs[nt] = 0.f;
#pragma unroll
        for (int mt = 0; mt < 2; ++mt)
#pragma unroll
            for (int r = 0; r < 4; ++r) rs[mt][r] = 0.f;
#pragma unroll
        for (int nt = 0; nt < 8; ++nt) {
            if (nt <= ntlim) {
                const int t = nt * 16 + row16;
                const bool msk = (t > qidx);
#pragma unroll
                for (int mt = 0; mt < 2; ++mt)
#pragma unroll
                    for (int r = 0; r < 4; ++r) {
                        float v = msk ? IGNORE_VAL : acc[mt][nt][r];
                        float p = __expf(v * (1.f / 64.f));
                        rs[mt][r] += p;
                        cs[nt] += p;
                    }
            }
        }

        // row sums across lane bits 0..3
#pragma unroll
        for (int m = 1; m < 16; m <<= 1)
#pragma unroll
            for (int mt = 0; mt < 2; ++mt)
#pragma unroll
                for (int r = 0; r < 4; ++r) rs[mt][r] += __shfl_xor(rs[mt][r], m, 64);
        if (row16 == 0) {
#pragma unroll
            for (int mt = 0; mt < 2; ++mt)
#pragma unroll
                for (int r = 0; r < 4; ++r)
                    Asm[qq][(wv * 2 + mt) * 16 + quad * 4 + r] = rs[mt][r];
        }

        // col sums across lane bits 4..5 -> per-wave partials (guarded, unrolled)
#pragma unroll
        for (int nt = 0; nt < 8; ++nt) {
            if (nt <= ntlim) {
#pragma unroll
                for (int m = 16; m < 64; m <<= 1) cs[nt] += __shfl_xor(cs[nt], m, 64);
            }
        }
        if (quad == 0) {
#pragma unroll
            for (int nt = 0; nt < 8; ++nt) Atp[qq][wv][nt * 16 + row16] = cs[nt];
        }

        float tot = rs[0][0] + rs[0][1] + rs[0][2] + rs[0][3]
                  + rs[1][0] + rs[1][1] + rs[1][2] + rs[1][3];
#pragma unroll
        for (int m = 16; m < 64; m <<= 1) tot += __shfl_xor(tot, m, 64);
        if (lane == 0) reds[qq][wv] = tot;
    }
    __syncthreads();

    for (int i = tid; i < QB * S_; i += 256) {
        const int qq = i >> 7, t = i & 127;
        Atm[qq][t] = Atp[qq][0][t] + Atp[qq][1][t] + Atp[qq][2][t] + Atp[qq][3][t];
    }
    __syncthreads();

    // epilogue, s-major: read va/vb rows once, FMA into 4 q-accumulators
    {
        const int h = tid & 63, w = tid >> 6;
        float za[QB] = {0.f, 0.f, 0.f, 0.f};
        for (int i = 0; i < 32; ++i) {
            const int s = w * 32 + i;
            const float va_v = va_h[(size_t)s * DH_ + h];
            const float vb_v = vb_h[(size_t)s * DH_ + h];
#pragma unroll
            for (int qq = 0; qq < QB; ++qq)
                za[qq] += Asm[qq][s] * va_v + Atm[qq][s] * vb_v;
        }
#pragma unroll
        for (int qq = 0; qq < QB; ++qq) zred[w][qq][h] = za[qq];
    }
    __syncthreads();

    {
        const int qq = tid >> 6, h = tid & 63;
        const float Zv = reds[qq][0] + reds[qq][1] + reds[qq][2] + reds[qq][3];
        float zv = zred[0][qq][h] + zred[1][qq][h] + zred[2][qq][h] + zred[3][qq][h];
        zv = zv / Zv + b_v[n * DH_ + h];
        z_bf[((size_t)(b * S_ + qg + 32 * qq) * (H_ * DH_)) + n * DH_ + h] = f2bf(zv);
    }
}

// ---------------- Kernel 3: out = z @ W_out + b_out (bf16 MFMA) -------------
// A = z_bf (256 x 512 bf16), W_out (512 x 512 f32). Tile 16 x 64, BK=64,
// grid (8, 16) = 128 blocks, 4 waves (wave w: cols w*16..w*16+15).
__global__ __launch_bounds__(256) void out_kernel(
    const unsigned short* __restrict__ z_bf,
    const float* __restrict__ W_out, const float* __restrict__ b_out,
    float* __restrict__ out)
{
    __shared__ __align__(16) unsigned short zs[16 * XT_ST];   // 2304 B
    __shared__ __align__(16) unsigned short Wt[64 * WT_ST];   // 8448 B

    const int cb = blockIdx.x;           // 0..7 (64 cols)
    const int rb = blockIdx.y;           // 0..15 (16 rows)
    const int tid = threadIdx.x;
    const int lane = tid & 63, wvx = tid >> 6;
    const int n16 = lane & 15, quad = lane >> 4;

    f32x4 acc = (f32x4){0.f, 0.f, 0.f, 0.f};

    for (int k0 = 0; k0 < 512; k0 += 64) {
        {   // stage z tile: 16 rows x 64 k, raw bf16 copy (uint2 = 4 elems/thread)
            const int m = tid >> 4, k4 = (tid & 15) * 4;
            uint2 v = *reinterpret_cast<const uint2*>(
                z_bf + (size_t)(rb * 16 + m) * 512 + k0 + k4);
            *reinterpret_cast<uint2*>(&zs[m * XT_ST + k4]) = v;
        }
        {   // stage W_out tile k-major
#pragma unroll
            for (int p = 0; p < 4; ++p) {
                const int k = p * 16 + (tid >> 4);
                const int nb = (tid & 15) * 4;
                const float4 v = *reinterpret_cast<const float4*>(
                    W_out + (size_t)(k0 + k) * 512 + cb * 64 + nb);
                *reinterpret_cast<unsigned int*>(&Wt[k * WT_ST + nb]) =
                    f2bf(v.x) | ((unsigned)f2bf(v.y) << 16);
                *reinterpret_cast<unsigned int*>(&Wt[k * WT_ST + nb + 2]) =
                    f2bf(v.z) | ((unsigned)f2bf(v.w) << 16);
            }
        }
        __syncthreads();
#pragma unroll
        for (int kk = 0; kk < 2; ++kk) {
            bf16x8 bf;
#pragma unroll
            for (int j = 0; j < 8; ++j)
                bf[j] = (short)Wt[(kk * 32 + quad * 8 + j) * WT_ST + wvx * 16 + n16];
            const bf16x8 af = *reinterpret_cast<const bf16x8*>(
                &zs[n16 * XT_ST + kk * 32 + quad * 8]);
            acc = __builtin_amdgcn_mfma_f32_16x16x32_bf16(af, bf, acc, 0, 0, 0);
        }
        __syncthreads();
    }

    const int c = cb * 64 + wvx * 16 + n16;
    const float bias = b_out[c];
#pragma unroll
    for (int r = 0; r < 4; ++r) {
        const int row = rb * 16 + quad * 4 + r;
        out[(size_t)row * 512 + c] = acc[r] + bias;
    }
}

// ---------------------------------------------------------------------------
extern "C" void kernel_launch(void* const* d_in, const int* in_sizes, int n_in,
                              void* d_out, int out_size, void* d_ws, size_t ws_size,
                              hipStream_t stream) {
    const float* x     = (const float*)d_in[0];
    const float* W_kkq = (const float*)d_in[1];
    const float* b_kkq = (const float*)d_in[2];
    const float* Wv_a  = (const float*)d_in[3];
    const float* Wv_b  = (const float*)d_in[4];
    const float* b_v   = (const float*)d_in[5];
    const float* W_out = (const float*)d_in[6];
    const float* b_out = (const float*)d_in[7];
    float* out = (float*)d_out;

    const size_t HE = (size_t)B_ * H_ * S_ * DH_;   // 131072
    float* ws = (float*)d_ws;
    float* k1_ws = ws;
    float* q_ws  = ws + HE;
    float* va_ws = ws + 2 * HE;
    float* vb_ws = ws + 3 * HE;
    unsigned short* k2bf = (unsigned short*)(ws + 4 * HE);          // HE ushorts
    unsigned short* z_bf = (unsigned short*)(ws + 4 * HE) + HE;     // HE ushorts

    proj_kernel<<<dim3(40, 8), 256, 0, stream>>>(x, W_kkq, b_kkq, Wv_a, Wv_b,
                                                 k1_ws, k2bf, q_ws, va_ws, vb_ws);
    tri_kernel<<<dim3(32, H_, B_), 256, 0, stream>>>(k1_ws, k2bf, q_ws,
                                                     va_ws, vb_ws, b_v, z_bf);
    out_kernel<<<dim3(8, 16), 256, 0, stream>>>(z_bf, W_out, b_out, out);
}

// Round 9
// 107.200 us; speedup vs baseline: 1.6157x; 1.0509x over previous
//
#include <hip/hip_runtime.h>
#include <hip/hip_bf16.h>

// Problem constants: B=2, S=128, D=512, H=8, Dh=64. All I/O float32 (R2/R3 evidence).
#define B_  2
#define S_  128
#define D_  512
#define H_  8
#define DH_ 64
#define IGNORE_VAL (-1.0e6f)
#define QB  4        // queries per tri block (interleaved: q = qg + 32*qq)

#define XT_ST 72     // ushort stride for LDS tiles (144 B rows: 16B-aligned for b128)

typedef __attribute__((ext_vector_type(8))) short bf16x8;   // MFMA A/B frag (4 VGPRs)
typedef __attribute__((ext_vector_type(4))) float f32x4;    // MFMA C/D frag

__device__ __forceinline__ unsigned short f2bf(float f) {
    unsigned int x = __float_as_uint(f);
    return (unsigned short)((x + 0x7fffu + ((x >> 16) & 1u)) >> 16);
}

// ---------------- Kernel 1: fused projection GEMM (bf16 MFMA) ---------------
// A = x (256 x 512), virtual W = [W_kkq | Wv_a | Wv_b] (512 x 2560).
// Tile 16 rows x 64 cols, BK=64, grid (40, 16) = 640 blocks (2.5/CU), 4 waves.
// Wt stored TRANSPOSED (n-major, stride XT_ST): B-frag = one ds_read_b128
// instead of 16 ds_read_u16 (R8 pattern).
// cb: 0..7 k1 | 8..15 k2 | 16..23 q | 24..31 va | 32..39 vb (head n = cb&7).
__global__ __launch_bounds__(256) void proj_kernel(
    const float* __restrict__ x,
    const float* __restrict__ W_kkq, const float* __restrict__ b_kkq,
    const float* __restrict__ Wv_a,  const float* __restrict__ Wv_b,
    float* __restrict__ k1_ws, unsigned short* __restrict__ k2bf, float* __restrict__ q_ws,
    float* __restrict__ va_ws, float* __restrict__ vb_ws)
{
    __shared__ __align__(16) unsigned short xs[16 * XT_ST];   // 2304 B
    __shared__ __align__(16) unsigned short Wt[64 * XT_ST];   // 9216 B (n-major!)

    const int cb = blockIdx.x;           // 0..39
    const int rb = blockIdx.y;           // 0..15 (16 rows)
    const int tid = threadIdx.x;
    const int lane = tid & 63, wvx = tid >> 6;
    const int n16 = lane & 15, quad = lane >> 4;

    const int part = cb >> 3;            // 0 k1, 1 k2, 2 q, 3 va, 4 vb
    const float* Wbase; int wstride; int wcoloff;
    if (part <= 2) { Wbase = W_kkq; wstride = 1536; wcoloff = cb * 64; }
    else if (part == 3) { Wbase = Wv_a; wstride = 512; wcoloff = (cb - 24) * 64; }
    else { Wbase = Wv_b; wstride = 512; wcoloff = (cb - 32) * 64; }

    f32x4 acc = (f32x4){0.f, 0.f, 0.f, 0.f};

    for (int k0 = 0; k0 < D_; k0 += 64) {
        if (tid < 128) {   // stage x tile: 16 rows x 64 k, f32 -> bf16, one uint4/thread
            const int m = tid >> 3, k8 = (tid & 7) * 8;
            const float* src = x + (size_t)(rb * 16 + m) * D_ + k0 + k8;
            const float4 a = *reinterpret_cast<const float4*>(src);
            const float4 b4 = *reinterpret_cast<const float4*>(src + 4);
            uint4 pk;
            pk.x = f2bf(a.x)  | ((unsigned)f2bf(a.y)  << 16);
            pk.y = f2bf(a.z)  | ((unsigned)f2bf(a.w)  << 16);
            pk.z = f2bf(b4.x) | ((unsigned)f2bf(b4.y) << 16);
            pk.w = f2bf(b4.z) | ((unsigned)f2bf(b4.w) << 16);
            *reinterpret_cast<uint4*>(&xs[m * XT_ST + k8]) = pk;
        }
        {   // stage W tile TRANSPOSED: Wt[n][k] = W[k][n]. Thread: k-pair kp, 4 n's.
#pragma unroll
            for (int p = 0; p < 2; ++p) {
                const int kp = (tid >> 4) + p * 16;   // 0..31
                const int k = kp * 2;
                const int nb = (tid & 15) * 4;
                const float4 v0 = *reinterpret_cast<const float4*>(
                    Wbase + (size_t)(k0 + k) * wstride + wcoloff + nb);
                const float4 v1 = *reinterpret_cast<const float4*>(
                    Wbase + (size_t)(k0 + k + 1) * wstride + wcoloff + nb);
                *reinterpret_cast<unsigned int*>(&Wt[(nb + 0) * XT_ST + k]) =
                    f2bf(v0.x) | ((unsigned)f2bf(v1.x) << 16);
                *reinterpret_cast<unsigned int*>(&Wt[(nb + 1) * XT_ST + k]) =
                    f2bf(v0.y) | ((unsigned)f2bf(v1.y) << 16);
                *reinterpret_cast<unsigned int*>(&Wt[(nb + 2) * XT_ST + k]) =
                    f2bf(v0.z) | ((unsigned)f2bf(v1.z) << 16);
                *reinterpret_cast<unsigned int*>(&Wt[(nb + 3) * XT_ST + k]) =
                    f2bf(v0.w) | ((unsigned)f2bf(v1.w) << 16);
            }
        }
        __syncthreads();
#pragma unroll
        for (int kk = 0; kk < 2; ++kk) {
            const bf16x8 bf = *reinterpret_cast<const bf16x8*>(
                &Wt[(wvx * 16 + n16) * XT_ST + kk * 32 + quad * 8]);
            const bf16x8 af = *reinterpret_cast<const bf16x8*>(
                &xs[n16 * XT_ST + kk * 32 + quad * 8]);
            acc = __builtin_amdgcn_mfma_f32_16x16x32_bf16(af, bf, acc, 0, 0, 0);
        }
        __syncthreads();
    }

    // epilogue: C row = quad*4 + r, col = wvx*16 + n16 (m89 layout)
    const int n_head = cb & 7;
    const int h = wvx * 16 + n16;
    const float bias = (part <= 2) ? b_kkq[cb * 64 + h] : 0.f;
    float* Obase = (part == 0) ? k1_ws : (part == 2) ? q_ws
                 : (part == 3) ? va_ws : vb_ws;
#pragma unroll
    for (int r = 0; r < 4; ++r) {
        const int row = rb * 16 + quad * 4 + r;       // b*128 + s
        const int b = row >> 7, s = row & 127;
        const size_t o = (((size_t)(b * H_ + n_head) * S_ + s) << 6) + h;
        const float val = acc[r] + bias;
        if (part == 1) k2bf[o] = f2bf(val);
        else           Obase[o] = val;
    }
}

// ---------------- Kernel 2: MFMA tri-scores + softmax marginals + z ---------
// Block = (4 interleaved q's, n, b), 256 thr = 4 waves. grid (32, 8, 2) = 512.
// q = qg + 32*qq. Causal skip via fully-unrolled nt loops + wave-uniform guard
// (R7 lesson: runtime bounds demote acc[] to scratch).
#define K2S 72   // ushort stride for k2 LDS rows
__global__ __launch_bounds__(256) void tri_kernel(
    const float* __restrict__ k1_ws, const unsigned short* __restrict__ k2bf,
    const float* __restrict__ q_ws,
    const float* __restrict__ va_ws, const float* __restrict__ vb_ws,
    const float* __restrict__ b_v,
    unsigned short* __restrict__ z_bf)
{
    const int qg = blockIdx.x;           // 0..31
    const int n = blockIdx.y;
    const int b = blockIdx.z;
    const int head = b * H_ + n;
    const float* k1h = k1_ws + (size_t)head * S_ * DH_;
    const unsigned short* k2hb = k2bf + (size_t)head * S_ * DH_;
    const float* qh = q_ws + (size_t)head * S_ * DH_;
    const float* va_h = va_ws + (size_t)head * S_ * DH_;
    const float* vb_h = vb_ws + (size_t)head * S_ * DH_;

    __shared__ __align__(16) unsigned short k2s[S_ * K2S];   // 18432 B
    __shared__ __align__(16) float qv[QB][DH_];
    __shared__ float Asm[QB][S_];
    __shared__ float Atm[QB][S_];
    __shared__ float Atp[QB][4][S_];
    __shared__ float reds[QB][4];
    __shared__ float zred[4][QB][DH_];

    const int tid = threadIdx.x;
    const int lane = tid & 63, wv = tid >> 6;
    const int row16 = lane & 15, quad = lane >> 4;

    if (tid < QB * DH_)
        qv[tid >> 6][tid & 63] = qh[(size_t)(qg + 32 * (tid >> 6)) * DH_ + (tid & 63)];
#pragma unroll
    for (int it = 0; it < 4; ++it) {
        const int i8 = (tid + it * 256) * 8;
        const int r = i8 >> 6, c = i8 & 63;
        uint4 v = *reinterpret_cast<const uint4*>(k2hb + i8);
        *reinterpret_cast<uint4*>(&k2s[r * K2S + c]) = v;
    }

    // k1 f32 fragments, kept across the q-loop. A[m=lane&15][k=quad*8+j]
    float k1f[2][2][8];
#pragma unroll
    for (int mt = 0; mt < 2; ++mt) {
        const int srow = (wv * 2 + mt) * 16 + row16;
#pragma unroll
        for (int kk = 0; kk < 2; ++kk) {
            const int k = kk * 32 + quad * 8;
            const float4 u0 = *reinterpret_cast<const float4*>(k1h + (size_t)srow * DH_ + k);
            const float4 u1 = *reinterpret_cast<const float4*>(k1h + (size_t)srow * DH_ + k + 4);
            k1f[mt][kk][0] = u0.x; k1f[mt][kk][1] = u0.y; k1f[mt][kk][2] = u0.z; k1f[mt][kk][3] = u0.w;
            k1f[mt][kk][4] = u1.x; k1f[mt][kk][5] = u1.y; k1f[mt][kk][6] = u1.z; k1f[mt][kk][7] = u1.w;
        }
    }
    __syncthreads();

    for (int qq = 0; qq < QB; ++qq) {
        const int qidx = qg + 32 * qq;
        const int ntlim = qidx >> 4;        // tiles nt > ntlim fully masked (exp = 0)

        bf16x8 afrag[2][2];
#pragma unroll
        for (int mt = 0; mt < 2; ++mt)
#pragma unroll
            for (int kk = 0; kk < 2; ++kk) {
                const int k = kk * 32 + quad * 8;
                bf16x8 f;
#pragma unroll
                for (int j = 0; j < 8; ++j)
                    f[j] = (short)f2bf(k1f[mt][kk][j] * qv[qq][k + j]);
                afrag[mt][kk] = f;
            }

        f32x4 acc[2][8];
#pragma unroll
        for (int mt = 0; mt < 2; ++mt)
#pragma unroll
            for (int nt = 0; nt < 8; ++nt) acc[mt][nt] = (f32x4){0.f, 0.f, 0.f, 0.f};
#pragma unroll
        for (int nt = 0; nt < 8; ++nt) {
            if (nt <= ntlim) {              // wave-uniform guard, indices compile-time
#pragma unroll
                for (int kk = 0; kk < 2; ++kk) {
                    bf16x8 bfrag = *reinterpret_cast<const bf16x8*>(
                        &k2s[(nt * 16 + row16) * K2S + kk * 32 + quad * 8]);
                    acc[0][nt] = __builtin_amdgcn_mfma_f32_16x16x32_bf16(afrag[0][kk], bfrag, acc[0][nt], 0, 0, 0);
                    acc[1][nt] = __builtin_amdgcn_mfma_f32_16x16x32_bf16(afrag[1][kk], bfrag, acc[1][nt], 0, 0, 0);
                }
            }
        }

        float rs[2][4], cs[8];
#pragma unroll
        for (int nt = 0; nt < 8; ++nt) cs[nt] = 0.f;
#pragma unroll
        for (int mt = 0; mt < 2; ++mt)
#pragma unroll
            for (int r = 0; r < 4; ++r) rs[mt][r] = 0.f;
#pragma unroll
        for (int nt = 0; nt < 8; ++nt) {
            if (nt <= ntlim) {
                const int t = nt * 16 + row16;
                const bool msk = (t > qidx);
#pragma unroll
                for (int mt = 0; mt < 2; ++mt)
#pragma unroll
                    for (int r = 0; r < 4; ++r) {
                        float v = msk ? IGNORE_VAL : acc[mt][nt][r];
                        float p = __expf(v * (1.f / 64.f));
                        rs[mt][r] += p;
                        cs[nt] += p;
                    }
            }
        }

        // row sums across lane bits 0..3
#pragma unroll
        for (int m = 1; m < 16; m <<= 1)
#pragma unroll
            for (int mt = 0; mt < 2; ++mt)
#pragma unroll
                for (int r = 0; r < 4; ++r) rs[mt][r] += __shfl_xor(rs[mt][r], m, 64);
        if (row16 == 0) {
#pragma unroll
            for (int mt = 0; mt < 2; ++mt)
#pragma unroll
                for (int r = 0; r < 4; ++r)
                    Asm[qq][(wv * 2 + mt) * 16 + quad * 4 + r] = rs[mt][r];
        }

        // col sums across lane bits 4..5 -> per-wave partials (guarded, unrolled)
#pragma unroll
        for (int nt = 0; nt < 8; ++nt) {
            if (nt <= ntlim) {
#pragma unroll
                for (int m = 16; m < 64; m <<= 1) cs[nt] += __shfl_xor(cs[nt], m, 64);
            }
        }
        if (quad == 0) {
#pragma unroll
            for (int nt = 0; nt < 8; ++nt) Atp[qq][wv][nt * 16 + row16] = cs[nt];
        }

        float tot = rs[0][0] + rs[0][1] + rs[0][2] + rs[0][3]
                  + rs[1][0] + rs[1][1] + rs[1][2] + rs[1][3];
#pragma unroll
        for (int m = 16; m < 64; m <<= 1) tot += __shfl_xor(tot, m, 64);
        if (lane == 0) reds[qq][wv] = tot;
    }
    __syncthreads();

    for (int i = tid; i < QB * S_; i += 256) {
        const int qq = i >> 7, t = i & 127;
        Atm[qq][t] = Atp[qq][0][t] + Atp[qq][1][t] + Atp[qq][2][t] + Atp[qq][3][t];
    }
    __syncthreads();

    // epilogue, s-major: read va/vb rows once, FMA into 4 q-accumulators
    {
        const int h = tid & 63, w = tid >> 6;
        float za[QB] = {0.f, 0.f, 0.f, 0.f};
        for (int i = 0; i < 32; ++i) {
            const int s = w * 32 + i;
            const float va_v = va_h[(size_t)s * DH_ + h];
            const float vb_v = vb_h[(size_t)s * DH_ + h];
#pragma unroll
            for (int qq = 0; qq < QB; ++qq)
                za[qq] += Asm[qq][s] * va_v + Atm[qq][s] * vb_v;
        }
#pragma unroll
        for (int qq = 0; qq < QB; ++qq) zred[w][qq][h] = za[qq];
    }
    __syncthreads();

    {
        const int qq = tid >> 6, h = tid & 63;
        const float Zv = reds[qq][0] + reds[qq][1] + reds[qq][2] + reds[qq][3];
        float zv = zred[0][qq][h] + zred[1][qq][h] + zred[2][qq][h] + zred[3][qq][h];
        zv = zv / Zv + b_v[n * DH_ + h];
        z_bf[((size_t)(b * S_ + qg + 32 * qq) * (H_ * DH_)) + n * DH_ + h] = f2bf(zv);
    }
}

// ---------------- Kernel 3: out = z @ W_out + b_out (bf16 MFMA) -------------
// A = z_bf (256 x 512 bf16), W_out (512 x 512 f32). Tile 16 x 64, BK=64,
// grid (8, 16) = 128 blocks, 4 waves. Wt transposed (n-major) for b128 B-frags.
__global__ __launch_bounds__(256) void out_kernel(
    const unsigned short* __restrict__ z_bf,
    const float* __restrict__ W_out, const float* __restrict__ b_out,
    float* __restrict__ out)
{
    __shared__ __align__(16) unsigned short zs[16 * XT_ST];   // 2304 B
    __shared__ __align__(16) unsigned short Wt[64 * XT_ST];   // 9216 B (n-major!)

    const int cb = blockIdx.x;           // 0..7 (64 cols)
    const int rb = blockIdx.y;           // 0..15 (16 rows)
    const int tid = threadIdx.x;
    const int lane = tid & 63, wvx = tid >> 6;
    const int n16 = lane & 15, quad = lane >> 4;

    f32x4 acc = (f32x4){0.f, 0.f, 0.f, 0.f};

    for (int k0 = 0; k0 < 512; k0 += 64) {
        {   // stage z tile: 16 rows x 64 k, raw bf16 copy (uint2 = 4 elems/thread)
            const int m = tid >> 4, k4 = (tid & 15) * 4;
            uint2 v = *reinterpret_cast<const uint2*>(
                z_bf + (size_t)(rb * 16 + m) * 512 + k0 + k4);
            *reinterpret_cast<uint2*>(&zs[m * XT_ST + k4]) = v;
        }
        {   // stage W_out tile TRANSPOSED: Wt[n][k] = W[k][n]
#pragma unroll
            for (int p = 0; p < 2; ++p) {
                const int kp = (tid >> 4) + p * 16;   // 0..31
                const int k = kp * 2;
                const int nb = (tid & 15) * 4;
                const float4 v0 = *reinterpret_cast<const float4*>(
                    W_out + (size_t)(k0 + k) * 512 + cb * 64 + nb);
                const float4 v1 = *reinterpret_cast<const float4*>(
                    W_out + (size_t)(k0 + k + 1) * 512 + cb * 64 + nb);
                *reinterpret_cast<unsigned int*>(&Wt[(nb + 0) * XT_ST + k]) =
                    f2bf(v0.x) | ((unsigned)f2bf(v1.x) << 16);
                *reinterpret_cast<unsigned int*>(&Wt[(nb + 1) * XT_ST + k]) =
                    f2bf(v0.y) | ((unsigned)f2bf(v1.y) << 16);
                *reinterpret_cast<unsigned int*>(&Wt[(nb + 2) * XT_ST + k]) =
                    f2bf(v0.z) | ((unsigned)f2bf(v1.z) << 16);
                *reinterpret_cast<unsigned int*>(&Wt[(nb + 3) * XT_ST + k]) =
                    f2bf(v0.w) | ((unsigned)f2bf(v1.w) << 16);
            }
        }
        __syncthreads();
#pragma unroll
        for (int kk = 0; kk < 2; ++kk) {
            const bf16x8 bf = *reinterpret_cast<const bf16x8*>(
                &Wt[(wvx * 16 + n16) * XT_ST + kk * 32 + quad * 8]);
            const bf16x8 af = *reinterpret_cast<const bf16x8*>(
                &zs[n16 * XT_ST + kk * 32 + quad * 8]);
            acc = __builtin_amdgcn_mfma_f32_16x16x32_bf16(af, bf, acc, 0, 0, 0);
        }
        __syncthreads();
    }

    const int c = cb * 64 + wvx * 16 + n16;
    const float bias = b_out[c];
#pragma unroll
    for (int r = 0; r < 4; ++r) {
        const int row = rb * 16 + quad * 4 + r;
        out[(size_t)row * 512 + c] = acc[r] + bias;
    }
}

// ---------------------------------------------------------------------------
extern "C" void kernel_launch(void* const* d_in, const int* in_sizes, int n_in,
                              void* d_out, int out_size, void* d_ws, size_t ws_size,
                              hipStream_t stream) {
    const float* x     = (const float*)d_in[0];
    const float* W_kkq = (const float*)d_in[1];
    const float* b_kkq = (const float*)d_in[2];
    const float* Wv_a  = (const float*)d_in[3];
    const float* Wv_b  = (const float*)d_in[4];
    const float* b_v   = (const float*)d_in[5];
    const float* W_out = (const float*)d_in[6];
    const float* b_out = (const float*)d_in[7];
    float* out = (float*)d_out;

    const size_t HE = (size_t)B_ * H_ * S_ * DH_;   // 131072
    float* ws = (float*)d_ws;
    float* k1_ws = ws;
    float* q_ws  = ws + HE;
    float* va_ws = ws + 2 * HE;
    float* vb_ws = ws + 3 * HE;
    unsigned short* k2bf = (unsigned short*)(ws + 4 * HE);          // HE ushorts
    unsigned short* z_bf = (unsigned short*)(ws + 4 * HE) + HE;     // HE ushorts

    proj_kernel<<<dim3(40, 16), 256, 0, stream>>>(x, W_kkq, b_kkq, Wv_a, Wv_b,
                                                  k1_ws, k2bf, q_ws, va_ws, vb_ws);
    tri_kernel<<<dim3(32, H_, B_), 256, 0, stream>>>(k1_ws, k2bf, q_ws,
                                                     va_ws, vb_ws, b_v, z_bf);
    out_kernel<<<dim3(8, 16), 256, 0, stream>>>(z_bf, W_out, b_out, out);
}